// Round 1
// baseline (156.709 us; speedup 1.0000x reference)
//
#include <hip/hip_runtime.h>
#include <math.h>

#define BLOCK 256
#define MAX_BLOCKS 2048
#define EPS 1e-10f
#define LAMBD 0.5f

// Reduction kernel: grid-stride over float4 chunks, accumulate
//   sse = sum((o-l)^2),  tp = sum(l * (o>0.5)),  sl = sum(l)
// Per-thread fp32 partials -> wave64 shuffle reduce -> LDS reduce -> atomicAdd.
__global__ __launch_bounds__(BLOCK) void detloss_reduce(
    const float* __restrict__ outp, const float* __restrict__ lab,
    float* __restrict__ acc, long long n) {

    const long long n4 = n >> 2;
    const float4* o4 = reinterpret_cast<const float4*>(outp);
    const float4* l4 = reinterpret_cast<const float4*>(lab);

    float sse = 0.f, tp = 0.f, sl = 0.f;

    const long long stride = (long long)gridDim.x * BLOCK;
    for (long long i = (long long)blockIdx.x * BLOCK + threadIdx.x; i < n4; i += stride) {
        float4 o = o4[i];
        float4 l = l4[i];
        float d0 = o.x - l.x, d1 = o.y - l.y, d2 = o.z - l.z, d3 = o.w - l.w;
        sse += d0 * d0 + d1 * d1 + d2 * d2 + d3 * d3;
        sl  += l.x + l.y + l.z + l.w;
        tp  += (o.x > 0.5f ? l.x : 0.f)
             + (o.y > 0.5f ? l.y : 0.f)
             + (o.z > 0.5f ? l.z : 0.f)
             + (o.w > 0.5f ? l.w : 0.f);
    }

    // Scalar tail (n not divisible by 4) — handled by thread 0 of block 0.
    if (blockIdx.x == 0 && threadIdx.x == 0) {
        for (long long i = n4 << 2; i < n; ++i) {
            float o = outp[i], l = lab[i];
            float d = o - l;
            sse += d * d;
            sl  += l;
            tp  += (o > 0.5f ? l : 0.f);
        }
    }

    // Wave-64 butterfly reduce.
    for (int off = 32; off > 0; off >>= 1) {
        sse += __shfl_down(sse, off);
        tp  += __shfl_down(tp,  off);
        sl  += __shfl_down(sl,  off);
    }

    __shared__ float s_sse[BLOCK / 64], s_tp[BLOCK / 64], s_sl[BLOCK / 64];
    const int lane = threadIdx.x & 63;
    const int wave = threadIdx.x >> 6;
    if (lane == 0) { s_sse[wave] = sse; s_tp[wave] = tp; s_sl[wave] = sl; }
    __syncthreads();

    if (threadIdx.x == 0) {
        float bsse = 0.f, btp = 0.f, bsl = 0.f;
        for (int w = 0; w < BLOCK / 64; ++w) {
            bsse += s_sse[w]; btp += s_tp[w]; bsl += s_sl[w];
        }
        atomicAdd(&acc[0], bsse);
        atomicAdd(&acc[1], btp);
        atomicAdd(&acc[2], bsl);
    }
}

// Scalar epilogue: coeff / log / mix.
__global__ void detloss_final(const float* __restrict__ acc,
                              float* __restrict__ out, float inv_n) {
    float sse = acc[0], tp = acc[1], sl = acc[2];
    float fn = sl - tp;
    float coeff;
    if (tp == 0.f && fn == 0.f)      coeff = 1.f;
    else if (tp == 0.f)              coeff = 0.f;
    else                             coeff = tp / (tp + fn);
    float cost = -logf(coeff + EPS);
    out[0] = sse * inv_n + LAMBD * cost;
}

extern "C" void kernel_launch(void* const* d_in, const int* in_sizes, int n_in,
                              void* d_out, int out_size, void* d_ws, size_t ws_size,
                              hipStream_t stream) {
    const float* outp = (const float*)d_in[0];
    const float* lab  = (const float*)d_in[1];
    float* out = (float*)d_out;
    float* acc = (float*)d_ws;

    long long n = (long long)in_sizes[0];

    // Zero the 3 accumulators (d_ws is poisoned, not re-zeroed between replays).
    hipMemsetAsync(acc, 0, 3 * sizeof(float), stream);

    long long n4 = n >> 2;
    int blocks = (int)((n4 + BLOCK - 1) / BLOCK);
    if (blocks > MAX_BLOCKS) blocks = MAX_BLOCKS;
    if (blocks < 1) blocks = 1;

    detloss_reduce<<<blocks, BLOCK, 0, stream>>>(outp, lab, acc, n);
    detloss_final<<<1, 1, 0, stream>>>(acc, out, 1.0f / (float)n);
}

// Round 2
// 141.118 us; speedup vs baseline: 1.1105x; 1.1105x over previous
//
#include <hip/hip_runtime.h>
#include <math.h>

#define BLOCK 256
#define MAX_BLOCKS 2048
#define UNROLL 4
#define EPS 1e-10f
#define LAMBD 0.5f

// Reduction kernel: grid-stride over float4 chunks, 4x unrolled with all 8
// loads issued before compute (MLP), accumulate
//   sse = sum((o-l)^2),  tp = sum(l * (o>0.5)),  sl = sum(l)
// Per-thread fp32 partials -> wave64 shuffle reduce -> LDS reduce -> atomicAdd.
__global__ __launch_bounds__(BLOCK) void detloss_reduce(
    const float* __restrict__ outp, const float* __restrict__ lab,
    float* __restrict__ acc, long long n) {

    const long long n4 = n >> 2;
    const float4* o4 = reinterpret_cast<const float4*>(outp);
    const float4* l4 = reinterpret_cast<const float4*>(lab);

    float sse = 0.f, tp = 0.f, sl = 0.f;

    const long long stride = (long long)gridDim.x * BLOCK;
    const long long chunk  = stride * UNROLL;
    const long long n_main = (n4 / chunk) * chunk;

    long long i = (long long)blockIdx.x * BLOCK + threadIdx.x;

    // Main unrolled loop: 8 independent float4 loads in flight per iteration.
    for (; i < n_main; i += chunk) {
        float4 o[UNROLL], l[UNROLL];
#pragma unroll
        for (int k = 0; k < UNROLL; ++k) {
            o[k] = o4[i + (long long)k * stride];
            l[k] = l4[i + (long long)k * stride];
        }
#pragma unroll
        for (int k = 0; k < UNROLL; ++k) {
            float d0 = o[k].x - l[k].x, d1 = o[k].y - l[k].y;
            float d2 = o[k].z - l[k].z, d3 = o[k].w - l[k].w;
            sse += d0 * d0 + d1 * d1 + d2 * d2 + d3 * d3;
            sl  += l[k].x + l[k].y + l[k].z + l[k].w;
            tp  += (o[k].x > 0.5f ? l[k].x : 0.f)
                 + (o[k].y > 0.5f ? l[k].y : 0.f)
                 + (o[k].z > 0.5f ? l[k].z : 0.f)
                 + (o[k].w > 0.5f ? l[k].w : 0.f);
        }
    }

    // Remainder float4s (grid-stride, un-unrolled).
    for (; i < n4; i += stride) {
        float4 o = o4[i];
        float4 l = l4[i];
        float d0 = o.x - l.x, d1 = o.y - l.y, d2 = o.z - l.z, d3 = o.w - l.w;
        sse += d0 * d0 + d1 * d1 + d2 * d2 + d3 * d3;
        sl  += l.x + l.y + l.z + l.w;
        tp  += (o.x > 0.5f ? l.x : 0.f)
             + (o.y > 0.5f ? l.y : 0.f)
             + (o.z > 0.5f ? l.z : 0.f)
             + (o.w > 0.5f ? l.w : 0.f);
    }

    // Scalar tail (n not divisible by 4) — thread 0 of block 0.
    if (blockIdx.x == 0 && threadIdx.x == 0) {
        for (long long j = n4 << 2; j < n; ++j) {
            float o = outp[j], l = lab[j];
            float d = o - l;
            sse += d * d;
            sl  += l;
            tp  += (o > 0.5f ? l : 0.f);
        }
    }

    // Wave-64 butterfly reduce.
    for (int off = 32; off > 0; off >>= 1) {
        sse += __shfl_down(sse, off);
        tp  += __shfl_down(tp,  off);
        sl  += __shfl_down(sl,  off);
    }

    __shared__ float s_sse[BLOCK / 64], s_tp[BLOCK / 64], s_sl[BLOCK / 64];
    const int lane = threadIdx.x & 63;
    const int wave = threadIdx.x >> 6;
    if (lane == 0) { s_sse[wave] = sse; s_tp[wave] = tp; s_sl[wave] = sl; }
    __syncthreads();

    if (threadIdx.x == 0) {
        float bsse = 0.f, btp = 0.f, bsl = 0.f;
        for (int w = 0; w < BLOCK / 64; ++w) {
            bsse += s_sse[w]; btp += s_tp[w]; bsl += s_sl[w];
        }
        atomicAdd(&acc[0], bsse);
        atomicAdd(&acc[1], btp);
        atomicAdd(&acc[2], bsl);
    }
}

// Scalar epilogue: coeff / log / mix.
__global__ void detloss_final(const float* __restrict__ acc,
                              float* __restrict__ out, float inv_n) {
    float sse = acc[0], tp = acc[1], sl = acc[2];
    float fn = sl - tp;
    float coeff;
    if (tp == 0.f && fn == 0.f)      coeff = 1.f;
    else if (tp == 0.f)              coeff = 0.f;
    else                             coeff = tp / (tp + fn);
    float cost = -logf(coeff + EPS);
    out[0] = sse * inv_n + LAMBD * cost;
}

extern "C" void kernel_launch(void* const* d_in, const int* in_sizes, int n_in,
                              void* d_out, int out_size, void* d_ws, size_t ws_size,
                              hipStream_t stream) {
    const float* outp = (const float*)d_in[0];
    const float* lab  = (const float*)d_in[1];
    float* out = (float*)d_out;
    float* acc = (float*)d_ws;

    long long n = (long long)in_sizes[0];

    // Zero the 3 accumulators (d_ws is poisoned, not re-zeroed between replays).
    hipMemsetAsync(acc, 0, 3 * sizeof(float), stream);

    long long n4 = n >> 2;
    int blocks = (int)((n4 + BLOCK - 1) / BLOCK);
    if (blocks > MAX_BLOCKS) blocks = MAX_BLOCKS;
    if (blocks < 1) blocks = 1;

    detloss_reduce<<<blocks, BLOCK, 0, stream>>>(outp, lab, acc, n);
    detloss_final<<<1, 1, 0, stream>>>(acc, out, 1.0f / (float)n);
}

// Round 3
// 103.293 us; speedup vs baseline: 1.5171x; 1.3662x over previous
//
#include <hip/hip_runtime.h>
#include <math.h>

#define BLOCK 256
#define NBLOCKS 2048
#define UNROLL 8
#define EPS 1e-10f
#define LAMBD 0.5f

// Per-element accumulate: sse += (o-l)^2, sl += l, tp += l*(o>0.5)
#define ACC(o, l)                                                         \
    do {                                                                  \
        float d0 = o.x - l.x, d1 = o.y - l.y;                             \
        float d2 = o.z - l.z, d3 = o.w - l.w;                             \
        sse += d0 * d0 + d1 * d1 + d2 * d2 + d3 * d3;                     \
        sl  += l.x + l.y + l.z + l.w;                                     \
        tp  += (o.x > 0.5f ? l.x : 0.f) + (o.y > 0.5f ? l.y : 0.f)        \
             + (o.z > 0.5f ? l.z : 0.f) + (o.w > 0.5f ? l.w : 0.f);       \
    } while (0)

// Grid-stride reduction, 8x unrolled: all 16 float4 loads issued as named
// variables BEFORE any compute so the compiler batches them (MLP).
// Block partials -> d_ws slots (no atomics, no memset needed).
__global__ __launch_bounds__(BLOCK, 4) void detloss_reduce(
    const float4* __restrict__ o4, const float4* __restrict__ l4,
    float* __restrict__ part, int n4, long long n,
    const float* __restrict__ outp, const float* __restrict__ lab) {

    float sse = 0.f, tp = 0.f, sl = 0.f;

    const int stride = gridDim.x * BLOCK;          // float4 units
    const int chunk  = stride * UNROLL;            // 2048*256*8 = 4.2M, fits int
    const int n_main = (n4 / chunk) * chunk;

    int i = blockIdx.x * BLOCK + threadIdx.x;

    for (; i < n_main; i += chunk) {
        // 16 independent loads, all issued before compute.
        float4 o0 = o4[i             ], l0 = l4[i             ];
        float4 o1 = o4[i +     stride], l1 = l4[i +     stride];
        float4 o2 = o4[i + 2 * stride], l2 = l4[i + 2 * stride];
        float4 o3 = o4[i + 3 * stride], l3 = l4[i + 3 * stride];
        float4 o4v= o4[i + 4 * stride], l4v= l4[i + 4 * stride];
        float4 o5 = o4[i + 5 * stride], l5 = l4[i + 5 * stride];
        float4 o6 = o4[i + 6 * stride], l6 = l4[i + 6 * stride];
        float4 o7 = o4[i + 7 * stride], l7 = l4[i + 7 * stride];
        ACC(o0, l0); ACC(o1, l1); ACC(o2, l2); ACC(o3, l3);
        ACC(o4v, l4v); ACC(o5, l5); ACC(o6, l6); ACC(o7, l7);
    }

    // Remainder float4s (grid-stride).
    for (; i < n4; i += stride) {
        float4 o = o4[i], l = l4[i];
        ACC(o, l);
    }

    // Scalar tail (n not divisible by 4) — thread 0 of block 0.
    if (blockIdx.x == 0 && threadIdx.x == 0) {
        for (long long j = (long long)n4 << 2; j < n; ++j) {
            float o = outp[j], l = lab[j];
            float d = o - l;
            sse += d * d;
            sl  += l;
            tp  += (o > 0.5f ? l : 0.f);
        }
    }

    // Wave-64 reduce.
    for (int off = 32; off > 0; off >>= 1) {
        sse += __shfl_down(sse, off);
        tp  += __shfl_down(tp,  off);
        sl  += __shfl_down(sl,  off);
    }

    __shared__ float s_sse[BLOCK / 64], s_tp[BLOCK / 64], s_sl[BLOCK / 64];
    const int lane = threadIdx.x & 63;
    const int wave = threadIdx.x >> 6;
    if (lane == 0) { s_sse[wave] = sse; s_tp[wave] = tp; s_sl[wave] = sl; }
    __syncthreads();

    if (threadIdx.x == 0) {
        float bsse = 0.f, btp = 0.f, bsl = 0.f;
        for (int w = 0; w < BLOCK / 64; ++w) {
            bsse += s_sse[w]; btp += s_tp[w]; bsl += s_sl[w];
        }
        const int nb = gridDim.x;
        part[blockIdx.x]          = bsse;
        part[nb + blockIdx.x]     = btp;
        part[2 * nb + blockIdx.x] = bsl;
    }
}

// Final: one 256-thread block reduces nblk x 3 partials + epilogue.
__global__ __launch_bounds__(256) void detloss_final(
    const float* __restrict__ part, int nblk,
    float* __restrict__ out, float inv_n) {

    float sse = 0.f, tp = 0.f, sl = 0.f;
    for (int i = threadIdx.x; i < nblk; i += 256) {
        sse += part[i];
        tp  += part[nblk + i];
        sl  += part[2 * nblk + i];
    }
    for (int off = 32; off > 0; off >>= 1) {
        sse += __shfl_down(sse, off);
        tp  += __shfl_down(tp,  off);
        sl  += __shfl_down(sl,  off);
    }
    __shared__ float s[3][4];
    const int lane = threadIdx.x & 63;
    const int wave = threadIdx.x >> 6;
    if (lane == 0) { s[0][wave] = sse; s[1][wave] = tp; s[2][wave] = sl; }
    __syncthreads();

    if (threadIdx.x == 0) {
        sse = s[0][0] + s[0][1] + s[0][2] + s[0][3];
        tp  = s[1][0] + s[1][1] + s[1][2] + s[1][3];
        sl  = s[2][0] + s[2][1] + s[2][2] + s[2][3];
        float fn = sl - tp;
        float coeff;
        if (tp == 0.f && fn == 0.f)      coeff = 1.f;
        else if (tp == 0.f)              coeff = 0.f;
        else                             coeff = tp / (tp + fn);
        float cost = -logf(coeff + EPS);
        out[0] = sse * inv_n + LAMBD * cost;
    }
}

extern "C" void kernel_launch(void* const* d_in, const int* in_sizes, int n_in,
                              void* d_out, int out_size, void* d_ws, size_t ws_size,
                              hipStream_t stream) {
    const float* outp = (const float*)d_in[0];
    const float* lab  = (const float*)d_in[1];
    float* out  = (float*)d_out;
    float* part = (float*)d_ws;   // 3 * NBLOCKS floats = 24 KB

    long long n = (long long)in_sizes[0];
    int n4 = (int)(n >> 2);

    int blocks = (n4 + BLOCK - 1) / BLOCK;
    if (blocks > NBLOCKS) blocks = NBLOCKS;
    if (blocks < 1) blocks = 1;

    detloss_reduce<<<blocks, BLOCK, 0, stream>>>(
        (const float4*)outp, (const float4*)lab, part, n4, n, outp, lab);
    detloss_final<<<1, 256, 0, stream>>>(part, blocks, out, 1.0f / (float)n);
}

// Round 4
// 99.926 us; speedup vs baseline: 1.5683x; 1.0337x over previous
//
#include <hip/hip_runtime.h>
#include <math.h>

#define BLOCK 256
#define NBLOCKS 2048
#define UNROLL 4
#define EPS 1e-10f
#define LAMBD 0.5f

// Per-element accumulate: sse += (o-l)^2, sl += l, tp += l*(o>0.5)
#define ACC(o, l)                                                         \
    do {                                                                  \
        float d0 = o.x - l.x, d1 = o.y - l.y;                             \
        float d2 = o.z - l.z, d3 = o.w - l.w;                             \
        sse += d0 * d0 + d1 * d1 + d2 * d2 + d3 * d3;                     \
        sl  += l.x + l.y + l.z + l.w;                                     \
        tp  += (o.x > 0.5f ? l.x : 0.f) + (o.y > 0.5f ? l.y : 0.f)        \
             + (o.z > 0.5f ? l.z : 0.f) + (o.w > 0.5f ? l.w : 0.f);       \
    } while (0)

// Grid-stride reduction, 4x unrolled. sched_barrier(0) between the load
// cluster and the compute cluster FORCES all 8 global_load_dwordx4 to issue
// before any VALU -> 8-deep MLP per wave (the compiler otherwise interleaves
// load->wait->compute with ~2 loads in flight; VGPR=36 evidence in R3).
__global__ __launch_bounds__(BLOCK, 4) void detloss_reduce(
    const float4* __restrict__ o4, const float4* __restrict__ l4,
    float* __restrict__ part, int n4, long long n,
    const float* __restrict__ outp, const float* __restrict__ lab) {

    float sse = 0.f, tp = 0.f, sl = 0.f;

    const int stride = gridDim.x * BLOCK;          // float4 units
    const int chunk  = stride * UNROLL;
    const int n_main = (n4 / chunk) * chunk;

    int i = blockIdx.x * BLOCK + threadIdx.x;

    for (; i < n_main; i += chunk) {
        // 8 independent 16B loads, pinned before any compute.
        float4 o0 = o4[i             ], l0 = l4[i             ];
        float4 o1 = o4[i +     stride], l1 = l4[i +     stride];
        float4 o2 = o4[i + 2 * stride], l2 = l4[i + 2 * stride];
        float4 o3 = o4[i + 3 * stride], l3 = l4[i + 3 * stride];
        __builtin_amdgcn_sched_barrier(0);   // loads above, compute below
        ACC(o0, l0); ACC(o1, l1); ACC(o2, l2); ACC(o3, l3);
    }

    // Remainder float4s (grid-stride).
    for (; i < n4; i += stride) {
        float4 o = o4[i], l = l4[i];
        ACC(o, l);
    }

    // Scalar tail (n not divisible by 4) — thread 0 of block 0.
    if (blockIdx.x == 0 && threadIdx.x == 0) {
        for (long long j = (long long)n4 << 2; j < n; ++j) {
            float o = outp[j], l = lab[j];
            float d = o - l;
            sse += d * d;
            sl  += l;
            tp  += (o > 0.5f ? l : 0.f);
        }
    }

    // Wave-64 reduce.
    for (int off = 32; off > 0; off >>= 1) {
        sse += __shfl_down(sse, off);
        tp  += __shfl_down(tp,  off);
        sl  += __shfl_down(sl,  off);
    }

    __shared__ float s_sse[BLOCK / 64], s_tp[BLOCK / 64], s_sl[BLOCK / 64];
    const int lane = threadIdx.x & 63;
    const int wave = threadIdx.x >> 6;
    if (lane == 0) { s_sse[wave] = sse; s_tp[wave] = tp; s_sl[wave] = sl; }
    __syncthreads();

    if (threadIdx.x == 0) {
        float bsse = 0.f, btp = 0.f, bsl = 0.f;
        for (int w = 0; w < BLOCK / 64; ++w) {
            bsse += s_sse[w]; btp += s_tp[w]; bsl += s_sl[w];
        }
        const int nb = gridDim.x;
        part[blockIdx.x]          = bsse;
        part[nb + blockIdx.x]     = btp;
        part[2 * nb + blockIdx.x] = bsl;
    }
}

// Final: one 256-thread block reduces nblk x 3 partials + epilogue.
__global__ __launch_bounds__(256) void detloss_final(
    const float* __restrict__ part, int nblk,
    float* __restrict__ out, float inv_n) {

    float sse = 0.f, tp = 0.f, sl = 0.f;
    for (int i = threadIdx.x; i < nblk; i += 256) {
        sse += part[i];
        tp  += part[nblk + i];
        sl  += part[2 * nblk + i];
    }
    for (int off = 32; off > 0; off >>= 1) {
        sse += __shfl_down(sse, off);
        tp  += __shfl_down(tp,  off);
        sl  += __shfl_down(sl,  off);
    }
    __shared__ float s[3][4];
    const int lane = threadIdx.x & 63;
    const int wave = threadIdx.x >> 6;
    if (lane == 0) { s[0][wave] = sse; s[1][wave] = tp; s[2][wave] = sl; }
    __syncthreads();

    if (threadIdx.x == 0) {
        sse = s[0][0] + s[0][1] + s[0][2] + s[0][3];
        tp  = s[1][0] + s[1][1] + s[1][2] + s[1][3];
        sl  = s[2][0] + s[2][1] + s[2][2] + s[2][3];
        float fn = sl - tp;
        float coeff;
        if (tp == 0.f && fn == 0.f)      coeff = 1.f;
        else if (tp == 0.f)              coeff = 0.f;
        else                             coeff = tp / (tp + fn);
        float cost = -logf(coeff + EPS);
        out[0] = sse * inv_n + LAMBD * cost;
    }
}

extern "C" void kernel_launch(void* const* d_in, const int* in_sizes, int n_in,
                              void* d_out, int out_size, void* d_ws, size_t ws_size,
                              hipStream_t stream) {
    const float* outp = (const float*)d_in[0];
    const float* lab  = (const float*)d_in[1];
    float* out  = (float*)d_out;
    float* part = (float*)d_ws;   // 3 * NBLOCKS floats = 24 KB

    long long n = (long long)in_sizes[0];
    int n4 = (int)(n >> 2);

    int blocks = (n4 + BLOCK - 1) / BLOCK;
    if (blocks > NBLOCKS) blocks = NBLOCKS;
    if (blocks < 1) blocks = 1;

    detloss_reduce<<<blocks, BLOCK, 0, stream>>>(
        (const float4*)outp, (const float4*)lab, part, n4, n, outp, lab);
    detloss_final<<<1, 256, 0, stream>>>(part, blocks, out, 1.0f / (float)n);
}